// Round 2
// baseline (425.729 us; speedup 1.0000x reference)
//
#include <hip/hip_runtime.h>

// 23-qubit batched complex state, 2x2 complex gate on qubit 12.
// DIM = 2^23, BATCH = 4. Axis-12 stride (row-major basis index) = 2^10 rows.
// out = stack([re, im]) of shape (2, DIM, BATCH), fp32.
//
// Pure streaming op: 256 MiB read + 256 MiB write, zero reuse.
// Floor at measured mixed-stream BW (~6.3 TB/s): ~85 us.
//
// This version: 4 pairs/thread, block-contiguous mapping. A block owns 1024
// consecutive pair indices = exactly one full `low` period (TBIT=10), so
// `high` is block-uniform and all 8 streams (4 load, 4 store) are single
// contiguous 16 KB regions per block. 16 nt-loads in flight per thread.

#define NQ 23
#define DIMQ (1 << NQ)
#define BATCH 4
#define TBIT 10        // 2^(23-1-12)
#define VPT 4          // pairs per thread
#define BLK 256
#define PAIRS (DIMQ / 2)

typedef float f4 __attribute__((ext_vector_type(4)));

__global__ __launch_bounds__(BLK) void gate_q12_kernel(
    const float* __restrict__ sre, const float* __restrict__ sim,
    const float* __restrict__ mre, const float* __restrict__ mim,
    float* __restrict__ out)
{
    // Block owns pairs [blockIdx.x*1024, +1024): low sweeps [0,1024), high const.
    const unsigned high = blockIdx.x;                  // pair_base >> TBIT
    const unsigned rowbase = high << (TBIT + 1);       // target-bit-0 row base

    // 2x2 gate coefficients (row-major, wave-uniform scalar loads).
    const float mr00 = mre[0], mr01 = mre[1], mr10 = mre[2], mr11 = mre[3];
    const float mi00 = mim[0], mi01 = mim[1], mi10 = mim[2], mi11 = mim[3];

    float* ore = out;                                  // out[0] = real plane
    float* oim = out + (size_t)DIMQ * BATCH;           // out[1] = imag plane

    f4 r0[VPT], r1[VPT], i0[VPT], i1[VPT];
    size_t o0[VPT], o1[VPT];

    // Issue all 16 loads first: max bytes in flight per wave.
#pragma unroll
    for (int j = 0; j < VPT; ++j) {
        const unsigned low = j * BLK + threadIdx.x;    // [0, 1024)
        const unsigned b0 = rowbase | low;             // target bit = 0
        const unsigned b1 = b0 | (1u << TBIT);         // target bit = 1
        o0[j] = (size_t)b0 * BATCH;
        o1[j] = (size_t)b1 * BATCH;
        r0[j] = __builtin_nontemporal_load((const f4*)(sre + o0[j]));
        r1[j] = __builtin_nontemporal_load((const f4*)(sre + o1[j]));
        i0[j] = __builtin_nontemporal_load((const f4*)(sim + o0[j]));
        i1[j] = __builtin_nontemporal_load((const f4*)(sim + o1[j]));
    }

#pragma unroll
    for (int j = 0; j < VPT; ++j) {
        const f4 a = r0[j], b = r1[j], c = i0[j], d = i1[j];
        const f4 or0 = mr00 * a + mr01 * b - (mi00 * c + mi01 * d);
        const f4 oi0 = mr00 * c + mr01 * d + (mi00 * a + mi01 * b);
        const f4 or1 = mr10 * a + mr11 * b - (mi10 * c + mi11 * d);
        const f4 oi1 = mr10 * c + mr11 * d + (mi10 * a + mi11 * b);
        __builtin_nontemporal_store(or0, (f4*)(ore + o0[j]));
        __builtin_nontemporal_store(or1, (f4*)(ore + o1[j]));
        __builtin_nontemporal_store(oi0, (f4*)(oim + o0[j]));
        __builtin_nontemporal_store(oi1, (f4*)(oim + o1[j]));
    }
}

extern "C" void kernel_launch(void* const* d_in, const int* in_sizes, int n_in,
                              void* d_out, int out_size, void* d_ws, size_t ws_size,
                              hipStream_t stream) {
    const float* sre = (const float*)d_in[0];
    const float* sim = (const float*)d_in[1];
    const float* mre = (const float*)d_in[2];
    const float* mim = (const float*)d_in[3];
    float* out = (float*)d_out;

    dim3 block(BLK);
    dim3 grid(PAIRS / (BLK * VPT));       // 4096 blocks, 1024 pairs each
    gate_q12_kernel<<<grid, block, 0, stream>>>(sre, sim, mre, mim, out);
}